// Round 4
// baseline (400.501 us; speedup 1.0000x reference)
//
#include <hip/hip_runtime.h>
#include <hip/hip_bf16.h>
#include <stdint.h>

typedef __attribute__((ext_vector_type(8))) short bf16x8;
typedef __attribute__((ext_vector_type(4))) float f32x4;

#define NSRC 100000
#define WIN_OFF 0                    // Win[0:256] A-frag pack, 128 KB
#define W1P_OFF (128*1024)           // W1 A-frag pack, 128 KB
#define BU_OFF  (256*1024)           // float b1[256] then float u[256]
#define SS_OFF  (BU_OFF + 2048)      // float S = b2.w0 + b_out0
#define Y_OFF   (264*1024)           // bf16 Y[NSRC][256] (512 B rows, natural group order)

#define AS3U32(p) ((__attribute__((address_space(3))) uint32_t*)(uintptr_t)(p))
#define AS1U32(p) ((const __attribute__((address_space(1))) uint32_t*)(uintptr_t)(p))

// Conflict-free tile layout: row r (512 B), feature-group g (16 B, 8 bf16) stored at
//   r*512 + xpos(r,g).  Bank-slot = (g+r)&7 -> any 8 consecutive lanes with
//   consecutive g (or consecutive r, fixed g) hit 8 distinct slots.
__device__ __forceinline__ int xpos(int r, int g) {
    return (((g) & 24) | (((g) + (r)) & 7)) << 4;
}

__device__ __forceinline__ unsigned int pkbf16(float a, float b) {
    __hip_bfloat162 h = __float22bfloat162_rn(make_float2(a, b));
    union { __hip_bfloat162 h; unsigned int u; } c; c.h = h; return c.u;
}

// ---------------- pack: A-frag weight packs, u = W2@w0, b1/u tables, S ----------------
__global__ __launch_bounds__(256) void pack_kernel(
    const float* __restrict__ Win, const float* __restrict__ W1,
    const float* __restrict__ W2, const float* __restrict__ Wout,
    const float* __restrict__ b1, const float* __restrict__ b2,
    const float* __restrict__ b_out, char* __restrict__ wp)
{
    const int t = threadIdx.x, blk = blockIdx.x;
    if (blk < 16) {                            // A-frag packs (coalesced row reads)
        const float* W = (blk < 8) ? Win : W1;
        char* dst = wp + ((blk < 8) ? WIN_OFF : W1P_OFF);
        const int c = blk & 7;
        #pragma unroll
        for (int q = 0; q < 4; ++q) {
            union { bf16x8 v; __hip_bfloat16 h[8]; } u;
            #pragma unroll
            for (int j = 0; j < 8; ++j)
                u.h[j] = __float2bfloat16(W[(size_t)(c*32 + q*8 + j)*256 + t]);
            *(bf16x8*)(dst + c*16384 + t*64 + q*16) = u.v;
        }
    } else if (blk < 24) {                     // u[f] = sum_n W2[f][n]*w0[n]
        __shared__ float w0s[256];
        w0s[t] = Wout[t*2];
        __syncthreads();
        const int b = blk - 16, fl = t >> 3, sub = t & 7, f = b*32 + fl;
        const float* row = W2 + (size_t)f*256 + sub*32;
        float p = 0.f;
        #pragma unroll
        for (int j = 0; j < 32; ++j) p += row[j]*w0s[sub*32 + j];
        p += __shfl_xor(p,1); p += __shfl_xor(p,2); p += __shfl_xor(p,4);
        if (sub == 0) {
            *(float*)(wp + BU_OFF + f*4) = b1[f];
            *(float*)(wp + BU_OFF + 1024 + f*4) = p;
        }
    } else {                                   // S = dot(b2,w0) + b_out0
        __shared__ float rb[4];
        float v = b2[t]*Wout[t*2];
        v += __shfl_xor(v,1); v += __shfl_xor(v,2); v += __shfl_xor(v,4);
        v += __shfl_xor(v,8); v += __shfl_xor(v,16); v += __shfl_xor(v,32);
        if ((t&63) == 0) rb[t>>6] = v;
        __syncthreads();
        if (t == 0) *(float*)(wp + SS_OFF) = rb[0]+rb[1]+rb[2]+rb[3] + b_out[0];
    }
}

// ---------------- Y[s] = latents[s] @ Win[0:256] + b_in (bf16, natural layout) -------
__global__ __launch_bounds__(256, 2) void precompute_y(
    const float* __restrict__ latents, const float* __restrict__ b_in,
    const char* __restrict__ wp, char* __restrict__ Yc)
{
    __shared__ __align__(16) char Xs[64 * 512];
    __shared__ float binS[256];
    const int tid = threadIdx.x, wave = tid >> 6, lane = tid & 63;
    const int q = lane >> 4, lm = lane & 15;

    bf16x8 wA[4][8];
    {
        const char* wb = wp + WIN_OFF;
        #pragma unroll
        for (int mt = 0; mt < 4; ++mt) {
            const int m = wave*64 + mt*16 + lm;
            #pragma unroll
            for (int c = 0; c < 8; ++c)
                wA[mt][c] = *(const bf16x8*)(wb + c*16384 + m*64 + q*16);
        }
    }
    binS[tid] = b_in[tid];

    const int ntY = (NSRC + 63) / 64;
    for (int tile = blockIdx.x; tile < ntY; tile += 512) {
        const int base = tile*64;
        // fully-coalesced fp32 loads: unit u = i*256+tid covers tile linearly
        #pragma unroll
        for (int i = 0; i < 8; ++i) {
            const int u = i*256 + tid;
            const int r = u >> 5, g = u & 31;
            int srow = base + r; if (srow >= NSRC) srow = NSRC - 1;
            const float4* lp = (const float4*)(latents + (size_t)srow*256 + g*8);
            float4 v0 = lp[0], v1 = lp[1];
            uint4 o;
            o.x = pkbf16(v0.x, v0.y); o.y = pkbf16(v0.z, v0.w);
            o.z = pkbf16(v1.x, v1.y); o.w = pkbf16(v1.z, v1.w);
            *(uint4*)(Xs + r*512 + xpos(r, g)) = o;
        }
        __syncthreads();
        f32x4 acc[4][4];
        #pragma unroll
        for (int mt = 0; mt < 4; ++mt)
            #pragma unroll
            for (int nt = 0; nt < 4; ++nt) acc[mt][nt] = (f32x4){0.f,0.f,0.f,0.f};
        #pragma unroll
        for (int c = 0; c < 8; ++c) {
            bf16x8 b[4];
            #pragma unroll
            for (int nt = 0; nt < 4; ++nt) {
                const int r = nt*16 + lm;
                b[nt] = *(const bf16x8*)(Xs + r*512 + xpos(r, c*4 + q));
            }
            #pragma unroll
            for (int mt = 0; mt < 4; ++mt)
                #pragma unroll
                for (int nt = 0; nt < 4; ++nt)
                    acc[mt][nt] = __builtin_amdgcn_mfma_f32_16x16x32_bf16(wA[mt][c], b[nt], acc[mt][nt], 0,0,0);
        }
        #pragma unroll
        for (int mt = 0; mt < 4; ++mt) {
            const int f0 = wave*64 + mt*16 + q*4;
            float4 bb = *(const float4*)&binS[f0];
            #pragma unroll
            for (int nt = 0; nt < 4; ++nt) {
                const int srow = base + nt*16 + lm;
                if (srow < NSRC) {
                    uint2 pk;
                    pk.x = pkbf16(acc[mt][nt][0] + bb.x, acc[mt][nt][1] + bb.y);
                    pk.y = pkbf16(acc[mt][nt][2] + bb.z, acc[mt][nt][3] + bb.w);
                    *(uint2*)(Yc + (size_t)srow*512 + f0*2) = pk;
                }
            }
        }
        __syncthreads();
    }
}

// ---- main: out[e] = relu( relu(Y[col]+pos@Wpos) @ W1 + b1 ) . u + S ----
__global__ __launch_bounds__(256, 2) void interp_main(
    const float* __restrict__ pos_src, const float* __restrict__ pos_tgt,
    const int* __restrict__ rowi, const int* __restrict__ coli,
    const float* __restrict__ Win, const char* __restrict__ wp,
    const char* __restrict__ Yc, float* __restrict__ out,
    int E, int ntiles)
{
    __shared__ __align__(16) char Xs[2][64 * 512];       // 65536
    __shared__ float wposI[32][24];                      // [g][dim*8+j]
    __shared__ float b1S[256], uS[256];
    __shared__ float posrel[2][64][4];
    __shared__ int   colsS[2][64];
    __shared__ float red[4][64];

    const int tid = threadIdx.x, wave = tid >> 6, lane = tid & 63;
    const int q = lane >> 4, lm = lane & 15;
    const int bid = blockIdx.x;
    const int p31 = lane & 31, h5 = lane >> 5;

    bf16x8 wA[4][8];                                     // W1 slice, loaded once
    {
        const char* wb = wp + W1P_OFF;
        #pragma unroll
        for (int mt = 0; mt < 4; ++mt) {
            const int m = wave*64 + mt*16 + lm;
            #pragma unroll
            for (int c = 0; c < 8; ++c)
                wA[mt][c] = *(const bf16x8*)(wb + c*16384 + m*64 + q*16);
        }
    }
    {
        #pragma unroll
        for (int s = 0; s < 3; ++s)
            wposI[tid >> 3][s*8 + (tid & 7)] = Win[(size_t)(256+s)*256 + tid];
        b1S[tid] = *(const float*)(wp + BU_OFF + tid*4);
        uS[tid]  = *(const float*)(wp + BU_OFF + 1024 + tid*4);
    }
    const float Sv = *(const float*)(wp + SS_OFF);
    const int niter = (ntiles - bid + 511) / 512;

    #pragma unroll
    for (int ii = 0; ii < 2; ++ii) {                     // meta for tiles 0,1
        if (tid < 64) {
            long tt = (long)bid + (long)ii*512; if (tt >= ntiles) tt = ntiles - 1;
            long e = tt*64 + tid; if (e >= E) e = E - 1;
            int ri = rowi[e], ci = coli[e];
            colsS[ii][tid] = ci;
            float4 pr;
            pr.x = pos_tgt[ri*3+0] - pos_src[ci*3+0];
            pr.y = pos_tgt[ri*3+1] - pos_src[ci*3+1];
            pr.z = pos_tgt[ri*3+2] - pos_src[ci*3+2];
            pr.w = 0.f;
            *(float4*)&posrel[ii][tid][0] = pr;
        }
    }
    __syncthreads();
    {                                                    // gather tile 0 -> Xs[0]
        #pragma unroll
        for (int k2 = 0; k2 < 8; ++k2) {
            const int r0 = wave*16 + k2*2;
            const int row = r0 + h5;
            const int cv = colsS[0][row];
            const int g = (p31 & 24) | ((p31 - row) & 7);      // inverse swizzle on src
            const char* src = Yc + (size_t)cv*512 + g*16;
            __builtin_amdgcn_global_load_lds(AS1U32(src), AS3U32(Xs[0] + r0*512), 16, 0, 0);
        }
    }

    // per-thread RMW ownership: feature-group gR (fixed), rows rbR*8 + i
    const int gR = tid & 31, rbR = tid >> 5;
    float2 wx[4], wy[4], wz[4];
    {
        const float* wi = &wposI[gR][0];
        #pragma unroll
        for (int d = 0; d < 4; ++d) {
            wx[d] = make_float2(wi[2*d],      wi[2*d+1]);
            wy[d] = make_float2(wi[8+2*d],    wi[8+2*d+1]);
            wz[d] = make_float2(wi[16+2*d],   wi[16+2*d+1]);
        }
    }

    for (int i = 0; i < niter; ++i) {
        const int p = i & 1;
        __syncthreads();                                 // A: gather(i) drained

        // ---- phase1 ----
        if (i > 0 && tid < 64) {                         // out-store tile i-1
            long e = ((long)bid + (long)(i-1)*512)*64 + tid;
            if (e < E) out[e] = red[0][tid]+red[1][tid]+red[2][tid]+red[3][tid] + Sv;
        }
        int m_ci = 0; float4 m_pr = {0.f,0.f,0.f,0.f};   // meta for tile i+2
        if (tid < 64) {
            long tt = (long)bid + (long)(i+2)*512; if (tt >= ntiles) tt = ntiles - 1;
            long e = tt*64 + tid; if (e >= E) e = E - 1;
            int ri = rowi[e]; m_ci = coli[e];
            m_pr.x = pos_tgt[ri*3+0] - pos_src[m_ci*3+0];
            m_pr.y = pos_tgt[ri*3+1] - pos_src[m_ci*3+1];
            m_pr.z = pos_tgt[ri*3+2] - pos_src[m_ci*3+2];
        }
        {                                                // pos-pass: Xs[p]=relu(Y+pos@Wpos)
            char* xb = Xs[p];
            #pragma unroll
            for (int it = 0; it < 8; ++it) {
                const int r = rbR*8 + it;
                float4 pr = *(const float4*)&posrel[p][r][0];
                char* addr = xb + r*512 + xpos(r, gR);
                uint4 raw = *(uint4*)addr;
                unsigned int rw[4] = {raw.x, raw.y, raw.z, raw.w};
                uint4 o;
                unsigned int ov[4];
                #pragma unroll
                for (int d = 0; d < 4; ++d) {
                    float lo = __uint_as_float(rw[d] << 16);
                    float hi = __uint_as_float(rw[d] & 0xffff0000u);
                    float vx = fmaf(pr.z, wz[d].x, fmaf(pr.y, wy[d].x, fmaf(pr.x, wx[d].x, lo)));
                    float vy = fmaf(pr.z, wz[d].y, fmaf(pr.y, wy[d].y, fmaf(pr.x, wx[d].y, hi)));
                    vx = fmaxf(vx, 0.f); vy = fmaxf(vy, 0.f);
                    ov[d] = pkbf16(vx, vy);
                }
                o.x = ov[0]; o.y = ov[1]; o.z = ov[2]; o.w = ov[3];
                *(uint4*)addr = o;
            }
        }
        __syncthreads();                                 // B: Xs[p] published

        // ---- phase2 ----
        {                                                // gather(i+1) -> Xs[1-p]
            const int s = 1 - p;
            char* xb = Xs[s];
            #pragma unroll
            for (int k2 = 0; k2 < 8; ++k2) {
                const int r0 = wave*16 + k2*2;
                const int row = r0 + h5;
                const int cv = colsS[s][row];
                const int g = (p31 & 24) | ((p31 - row) & 7);
                const char* src = Yc + (size_t)cv*512 + g*16;
                __builtin_amdgcn_global_load_lds(AS1U32(src), AS3U32(xb + r0*512), 16, 0, 0);
            }
        }
        f32x4 acc[4][4];
        #pragma unroll
        for (int mt = 0; mt < 4; ++mt)
            #pragma unroll
            for (int nt = 0; nt < 4; ++nt) acc[mt][nt] = (f32x4){0.f,0.f,0.f,0.f};
        {
            const char* xb = Xs[p];
            #pragma unroll
            for (int c = 0; c < 8; ++c) {
                bf16x8 b[4];
                #pragma unroll
                for (int nt = 0; nt < 4; ++nt) {
                    const int r = nt*16 + lm;
                    b[nt] = *(const bf16x8*)(xb + r*512 + xpos(r, c*4 + q));
                }
                #pragma unroll
                for (int mt = 0; mt < 4; ++mt)
                    #pragma unroll
                    for (int nt = 0; nt < 4; ++nt)
                        acc[mt][nt] = __builtin_amdgcn_mfma_f32_16x16x32_bf16(wA[mt][c], b[nt], acc[mt][nt], 0,0,0);
            }
        }
        float2 p2[4] = {{0.f,0.f},{0.f,0.f},{0.f,0.f},{0.f,0.f}};
        #pragma unroll
        for (int mt = 0; mt < 4; ++mt) {
            const int f0 = wave*64 + mt*16 + q*4;
            float2 bA = *(const float2*)&b1S[f0], bB = *(const float2*)&b1S[f0+2];
            float2 uA = *(const float2*)&uS[f0],  uB = *(const float2*)&uS[f0+2];
            #pragma unroll
            for (int nt = 0; nt < 4; ++nt) {
                float hx = fmaxf(acc[mt][nt][0] + bA.x, 0.f);
                float hy = fmaxf(acc[mt][nt][1] + bA.y, 0.f);
                float hz = fmaxf(acc[mt][nt][2] + bB.x, 0.f);
                float hw = fmaxf(acc[mt][nt][3] + bB.y, 0.f);
                p2[nt].x = fmaf(hx, uA.x, p2[nt].x);
                p2[nt].y = fmaf(hy, uA.y, p2[nt].y);
                p2[nt].x = fmaf(hz, uB.x, p2[nt].x);
                p2[nt].y = fmaf(hw, uB.y, p2[nt].y);
            }
        }
        #pragma unroll
        for (int nt = 0; nt < 4; ++nt) {
            float v = p2[nt].x + p2[nt].y;
            v += __shfl_xor(v, 16);
            v += __shfl_xor(v, 32);
            if (lane < 16) red[wave][nt*16 + lane] = v;
        }
        if (tid < 64) {                                  // meta writes for i+2 (slot p)
            colsS[p][tid] = m_ci;
            *(float4*)&posrel[p][tid][0] = m_pr;
        }
    }
    __syncthreads();
    if (tid < 64) {
        long e = ((long)bid + (long)(niter-1)*512)*64 + tid;
        if (e < E) out[e] = red[0][tid]+red[1][tid]+red[2][tid]+red[3][tid] + Sv;
    }
}

extern "C" void kernel_launch(void* const* d_in, const int* in_sizes, int n_in,
                              void* d_out, int out_size, void* d_ws, size_t ws_size,
                              hipStream_t stream)
{
    const float* pos_src = (const float*)d_in[0];
    const float* pos_tgt = (const float*)d_in[1];
    const float* latents = (const float*)d_in[2];
    const int*   rowi    = (const int*)d_in[3];
    const int*   coli    = (const int*)d_in[4];
    const float* Win     = (const float*)d_in[5];
    const float* b_in    = (const float*)d_in[6];
    const float* W1      = (const float*)d_in[7];
    const float* b1      = (const float*)d_in[8];
    const float* W2      = (const float*)d_in[9];
    const float* b2      = (const float*)d_in[10];
    const float* Wout    = (const float*)d_in[11];
    const float* b_out   = (const float*)d_in[12];
    float* out = (float*)d_out;
    const int E = in_sizes[3];
    const int ntiles = (E + 63) / 64;

    char* wp = (char*)d_ws;                  // packs ~264 KB + Y 51.2 MB
    char* Yc = wp + Y_OFF;

    pack_kernel<<<25, 256, 0, stream>>>(Win, W1, W2, Wout, b1, b2, b_out, wp);
    precompute_y<<<512, 256, 0, stream>>>(latents, b_in, wp, Yc);
    interp_main<<<512, 256, 0, stream>>>(pos_src, pos_tgt, rowi, coli,
                                         Win, wp, Yc, out, E, ntiles);
}

// Round 6
// 333.752 us; speedup vs baseline: 1.2000x; 1.2000x over previous
//
#include <hip/hip_runtime.h>
#include <hip/hip_bf16.h>
#include <stdint.h>

typedef __attribute__((ext_vector_type(8))) short bf16x8;
typedef __attribute__((ext_vector_type(4))) float f32x4;

#define NSRC 100000
#define WIN_OFF 0                    // Win[0:256] A-frag pack, 128 KB
#define W1P_OFF (128*1024)           // W1 A-frag pack, 128 KB
#define BU_OFF  (256*1024)           // float b1[256] then float u[256]
#define SS_OFF  (BU_OFF + 2048)      // float S = b2.w0 + b_out0
#define Y_OFF   (264*1024)           // bf16 Y[NSRC][256] (512 B natural rows)

// Pair-stride layout: row-pair t at t*1040. 1040 = 65*16, 65 odd -> 16-B slot
// index = ((r>>1) + g) & 7 (natural rotation, no explicit skew, NO OVERLAP --
// R5's PBASE(t)=t*1024+(t&7)*16 aliased pair 7 tail with pair 8 head: the bug).
// DMA-compatible: uniform pair base, lane*16 contiguous; source rows contiguous.
#define PBASE(t) ((t)*1040)
#define XOFF(r,g) (PBASE((r)>>1) + ((r)&1)*512 + (g)*16)
#define XBUF (16*1040)               // 16 row-pairs = 32 rows, 16640 B

// natural-row scratch swizzle (precompute transpose): group g of row r:
__device__ __forceinline__ int xpos(int r, int g) {
    return (((g) & 24) | (((g) + (r)) & 7)) << 4;
}

#define AS3U32(p) ((__attribute__((address_space(3))) uint32_t*)(uintptr_t)(p))
#define AS1U32(p) ((const __attribute__((address_space(1))) uint32_t*)(uintptr_t)(p))

__device__ __forceinline__ unsigned int pkbf16(float a, float b) {
    __hip_bfloat162 h = __float22bfloat162_rn(make_float2(a, b));
    union { __hip_bfloat162 h; unsigned int u; } c; c.h = h; return c.u;
}

// ---------------- pack: A-frag weight packs, u = W2@w0, b1/u tables, S ----------------
__global__ __launch_bounds__(256) void pack_kernel(
    const float* __restrict__ Win, const float* __restrict__ W1,
    const float* __restrict__ W2, const float* __restrict__ Wout,
    const float* __restrict__ b1, const float* __restrict__ b2,
    const float* __restrict__ b_out, char* __restrict__ wp)
{
    const int t = threadIdx.x, blk = blockIdx.x;
    if (blk < 16) {                            // A-frag packs (coalesced row reads)
        const float* W = (blk < 8) ? Win : W1;
        char* dst = wp + ((blk < 8) ? WIN_OFF : W1P_OFF);
        const int c = blk & 7;
        #pragma unroll
        for (int q = 0; q < 4; ++q) {
            union { bf16x8 v; __hip_bfloat16 h[8]; } u;
            #pragma unroll
            for (int j = 0; j < 8; ++j)
                u.h[j] = __float2bfloat16(W[(size_t)(c*32 + q*8 + j)*256 + t]);
            *(bf16x8*)(dst + c*16384 + t*64 + q*16) = u.v;
        }
    } else if (blk < 24) {                     // u[f] = sum_n W2[f][n]*w0[n]
        __shared__ float w0s[256];
        w0s[t] = Wout[t*2];
        __syncthreads();
        const int b = blk - 16, fl = t >> 3, sub = t & 7, f = b*32 + fl;
        const float* row = W2 + (size_t)f*256 + sub*32;
        float p = 0.f;
        #pragma unroll
        for (int j = 0; j < 32; ++j) p += row[j]*w0s[sub*32 + j];
        p += __shfl_xor(p,1); p += __shfl_xor(p,2); p += __shfl_xor(p,4);
        if (sub == 0) {
            *(float*)(wp + BU_OFF + f*4) = b1[f];
            *(float*)(wp + BU_OFF + 1024 + f*4) = p;
        }
    } else {                                   // S = dot(b2,w0) + b_out0
        __shared__ float rb[4];
        float v = b2[t]*Wout[t*2];
        v += __shfl_xor(v,1); v += __shfl_xor(v,2); v += __shfl_xor(v,4);
        v += __shfl_xor(v,8); v += __shfl_xor(v,16); v += __shfl_xor(v,32);
        if ((t&63) == 0) rb[t>>6] = v;
        __syncthreads();
        if (t == 0) *(float*)(wp + SS_OFF) = rb[0]+rb[1]+rb[2]+rb[3] + b_out[0];
    }
}

// ---------------- Y[s] = latents[s] @ Win[0:256] + b_in (bf16 rows, coalesced) -------
__global__ __launch_bounds__(512, 4) void precompute_y(
    const float* __restrict__ latents, const float* __restrict__ b_in,
    const char* __restrict__ wp, char* __restrict__ Yc)
{
    __shared__ __align__(16) char Xs[2][XBUF];
    __shared__ float binS[256];
    const int tid = threadIdx.x, wave = tid >> 6, lane = tid & 63;
    const int q = lane >> 4, lm = lane & 15;
    const int rA = tid >> 5, gA = tid & 31;        // unit mapping (it*16 + rA rows)

    bf16x8 wA[2][8];                               // Win slice: 32 feats/wave
    {
        const char* wb = wp + WIN_OFF;
        #pragma unroll
        for (int mt = 0; mt < 2; ++mt) {
            const int m = wave*32 + mt*16 + lm;
            #pragma unroll
            for (int c = 0; c < 8; ++c)
                wA[mt][c] = *(const bf16x8*)(wb + c*16384 + m*64 + q*16);
        }
    }
    if (tid < 256) binS[tid] = b_in[tid];

    const int NT = (NSRC + 31) / 32;

    // prologue: load + pack tile bid -> Xs[0]
    #pragma unroll
    for (int it = 0; it < 2; ++it) {
        const int r = it*16 + rA;
        int srow = blockIdx.x*32 + r; if (srow >= NSRC) srow = NSRC - 1;
        const float4* lp = (const float4*)(latents + (size_t)srow*256 + gA*8);
        float4 v0 = lp[0], v1 = lp[1];
        uint4 o;
        o.x = pkbf16(v0.x, v0.y); o.y = pkbf16(v0.z, v0.w);
        o.z = pkbf16(v1.x, v1.y); o.w = pkbf16(v1.z, v1.w);
        *(uint4*)(Xs[0] + XOFF(r, gA)) = o;
    }
    __syncthreads();

    int pp = 0;
    for (int tile = blockIdx.x; tile < NT; tile += 512) {
        // prefetch next tile's latents into registers
        float4 Ln[2][2];
        {
            int tn = tile + 512; if (tn >= NT) tn = NT - 1;
            #pragma unroll
            for (int it = 0; it < 2; ++it) {
                const int r = it*16 + rA;
                int srow = tn*32 + r; if (srow >= NSRC) srow = NSRC - 1;
                const float4* lp = (const float4*)(latents + (size_t)srow*256 + gA*8);
                Ln[it][0] = lp[0]; Ln[it][1] = lp[1];
            }
        }
        // MFMA on Xs[pp]
        f32x4 acc[2][2];
        #pragma unroll
        for (int mt = 0; mt < 2; ++mt)
            #pragma unroll
            for (int nt = 0; nt < 2; ++nt) acc[mt][nt] = (f32x4){0.f,0.f,0.f,0.f};
        {
            const char* xb = Xs[pp];
            #pragma unroll
            for (int c = 0; c < 8; ++c) {
                bf16x8 b0  = *(const bf16x8*)(xb + XOFF(lm,      c*4 + q));
                bf16x8 b1v = *(const bf16x8*)(xb + XOFF(16 + lm, c*4 + q));
                #pragma unroll
                for (int mt = 0; mt < 2; ++mt) {
                    acc[mt][0] = __builtin_amdgcn_mfma_f32_16x16x32_bf16(wA[mt][c], b0,  acc[mt][0], 0,0,0);
                    acc[mt][1] = __builtin_amdgcn_mfma_f32_16x16x32_bf16(wA[mt][c], b1v, acc[mt][1], 0,0,0);
                }
            }
        }
        __syncthreads();                           // all reads of Xs[pp] done
        // transpose: acc -> Xs[pp] natural rows (xpos swizzle), bias added
        #pragma unroll
        for (int mt = 0; mt < 2; ++mt) {
            const int f0 = wave*32 + mt*16 + q*4;
            const int g0 = f0 >> 3, sub = (f0 & 7)*2;
            float4 bb = *(const float4*)&binS[f0];
            #pragma unroll
            for (int nt = 0; nt < 2; ++nt) {
                const int r = nt*16 + lm;
                uint2 val;
                val.x = pkbf16(acc[mt][nt][0] + bb.x, acc[mt][nt][1] + bb.y);
                val.y = pkbf16(acc[mt][nt][2] + bb.z, acc[mt][nt][3] + bb.w);
                *(uint2*)(Xs[pp] + r*512 + xpos(r, g0) + sub) = val;
            }
        }
        __syncthreads();
        // readback -> coalesced global row stores; pack prefetch -> Xs[1-pp]
        #pragma unroll
        for (int it = 0; it < 2; ++it) {
            const int r = it*16 + rA;
            uint4 v = *(uint4*)(Xs[pp] + r*512 + xpos(r, gA));
            const int srow = tile*32 + r;
            if (srow < NSRC)
                *(uint4*)(Yc + (size_t)srow*512 + gA*16) = v;
            uint4 o;
            o.x = pkbf16(Ln[it][0].x, Ln[it][0].y); o.y = pkbf16(Ln[it][0].z, Ln[it][0].w);
            o.z = pkbf16(Ln[it][1].x, Ln[it][1].y); o.w = pkbf16(Ln[it][1].z, Ln[it][1].w);
            *(uint4*)(Xs[1-pp] + XOFF(r, gA)) = o;
        }
        __syncthreads();
        pp ^= 1;
    }
}

// ---- main: out[e] = relu( relu(Y[col]+pos@Wpos) @ W1 + b1 ) . u + S ----
__global__ __launch_bounds__(512, 4) void interp_main(
    const float* __restrict__ pos_src, const float* __restrict__ pos_tgt,
    const int* __restrict__ rowi, const int* __restrict__ coli,
    const float* __restrict__ Win, const char* __restrict__ wp,
    const char* __restrict__ Yc, float* __restrict__ out,
    int E, int ntiles)
{
    __shared__ __align__(16) char Xs[2][XBUF];     // 33280
    __shared__ float wposI[32][28];                // [g][dim*8+j], stride 28 -> CF reads
    __shared__ float b1S[256], uS[256];
    __shared__ float posrel[2][32][4];
    __shared__ int   colsS[2][32];
    __shared__ float red[8][32];

    const int tid = threadIdx.x, wave = tid >> 6, lane = tid & 63;
    const int q = lane >> 4, lm = lane & 15;
    const int p31 = lane & 31, h5 = lane >> 5;
    const int bid = blockIdx.x;

    bf16x8 wA[2][8];                               // W1 slice: 32 feats/wave, 64 VGPR
    {
        const char* wb = wp + W1P_OFF;
        #pragma unroll
        for (int mt = 0; mt < 2; ++mt) {
            const int m = wave*32 + mt*16 + lm;
            #pragma unroll
            for (int c = 0; c < 8; ++c)
                wA[mt][c] = *(const bf16x8*)(wb + c*16384 + m*64 + q*16);
        }
    }
    if (tid < 256) {
        #pragma unroll
        for (int s = 0; s < 3; ++s)
            wposI[tid >> 3][s*8 + (tid & 7)] = Win[(size_t)(256+s)*256 + tid];
        b1S[tid] = *(const float*)(wp + BU_OFF + tid*4);
        uS[tid]  = *(const float*)(wp + BU_OFF + 1024 + tid*4);
    }
    const float Sv = *(const float*)(wp + SS_OFF);
    const int niter = (ntiles - bid + 511) / 512;

    #pragma unroll
    for (int ii = 0; ii < 2; ++ii) {               // meta for tiles 0,1
        if (tid < 32) {
            long tt = (long)bid + (long)ii*512; if (tt >= ntiles) tt = ntiles - 1;
            long e = tt*32 + tid; if (e >= E) e = E - 1;
            int ri = rowi[e], ci = coli[e];
            colsS[ii][tid] = ci;
            float4 pr;
            pr.x = pos_tgt[ri*3+0] - pos_src[ci*3+0];
            pr.y = pos_tgt[ri*3+1] - pos_src[ci*3+1];
            pr.z = pos_tgt[ri*3+2] - pos_src[ci*3+2];
            pr.w = 0.f;
            *(float4*)&posrel[ii][tid][0] = pr;
        }
    }
    __syncthreads();
    {                                              // gather tile 0 -> Xs[0], CONTIGUOUS src
        #pragma unroll
        for (int k2 = 0; k2 < 2; ++k2) {
            const int t = wave*2 + k2;
            const int cv = colsS[0][2*t + h5];
            const char* src = Yc + (size_t)cv*512 + p31*16;
            __builtin_amdgcn_global_load_lds(AS1U32(src), AS3U32(Xs[0] + PBASE(t)), 16, 0, 0);
        }
    }

    const int gR = tid & 31, rhB = tid >> 5;       // pos-pass ownership

    for (int i = 0; i < niter; ++i) {
        const int p = i & 1;
        __syncthreads();                           // A: gather(i) drained, Xs[p] ready

        // ---- phase 1 ----
        if (i > 0 && tid < 32) {                   // out-store tile i-1
            long e = ((long)bid + (long)(i-1)*512)*32 + tid;
            if (e < E) {
                float s = Sv;
                #pragma unroll
                for (int w = 0; w < 8; ++w) s += red[w][tid];
                out[e] = s;
            }
        }
        int m_ci = 0; float4 m_pr = {0.f,0.f,0.f,0.f};
        if (tid < 32) {                            // meta prefetch for tile i+2
            long tt = (long)bid + (long)(i+2)*512; if (tt >= ntiles) tt = ntiles - 1;
            long e = tt*32 + tid; if (e >= E) e = E - 1;
            int ri = rowi[e]; m_ci = coli[e];
            m_pr.x = pos_tgt[ri*3+0] - pos_src[m_ci*3+0];
            m_pr.y = pos_tgt[ri*3+1] - pos_src[m_ci*3+1];
            m_pr.z = pos_tgt[ri*3+2] - pos_src[m_ci*3+2];
        }
        {                                          // pos-pass: Xs[p] = relu(Y + pos@Wpos)
            float wv[24];
            {
                const float* wr = &wposI[gR][0];
                #pragma unroll
                for (int k = 0; k < 6; ++k) {
                    float4 t4 = *(const float4*)(wr + k*4);
                    wv[k*4] = t4.x; wv[k*4+1] = t4.y; wv[k*4+2] = t4.z; wv[k*4+3] = t4.w;
                }
            }
            char* xb = Xs[p];
            #pragma unroll
            for (int it = 0; it < 2; ++it) {
                const int r = it*16 + rhB;
                float4 pr = *(const float4*)&posrel[p][r][0];
                char* addr = xb + XOFF(r, gR);
                uint4 raw = *(uint4*)addr;
                unsigned int rw[4] = {raw.x, raw.y, raw.z, raw.w};
                unsigned int ov[4];
                #pragma unroll
                for (int d = 0; d < 4; ++d) {
                    float lo = __uint_as_float(rw[d] << 16);
                    float hi = __uint_as_float(rw[d] & 0xffff0000u);
                    float vx = fmaf(pr.z, wv[16+2*d],   fmaf(pr.y, wv[8+2*d],   fmaf(pr.x, wv[2*d],   lo)));
                    float vy = fmaf(pr.z, wv[16+2*d+1], fmaf(pr.y, wv[8+2*d+1], fmaf(pr.x, wv[2*d+1], hi)));
                    ov[d] = pkbf16(fmaxf(vx, 0.f), fmaxf(vy, 0.f));
                }
                uint4 o; o.x = ov[0]; o.y = ov[1]; o.z = ov[2]; o.w = ov[3];
                *(uint4*)addr = o;
            }
        }
        __syncthreads();                           // B: Xs[p] published

        // ---- phase 2 ----
        {                                          // gather(i+1) -> Xs[1-p], in flight over MFMA
            const int s = 1 - p;
            #pragma unroll
            for (int k2 = 0; k2 < 2; ++k2) {
                const int t = wave*2 + k2;
                const int cv = colsS[s][2*t + h5];
                const char* src = Yc + (size_t)cv*512 + p31*16;
                __builtin_amdgcn_global_load_lds(AS1U32(src), AS3U32(Xs[s] + PBASE(t)), 16, 0, 0);
            }
        }
        f32x4 acc[2][2];
        #pragma unroll
        for (int mt = 0; mt < 2; ++mt)
            #pragma unroll
            for (int nt = 0; nt < 2; ++nt) acc[mt][nt] = (f32x4){0.f,0.f,0.f,0.f};
        {
            const char* xb = Xs[p];
            #pragma unroll
            for (int c = 0; c < 8; ++c) {
                bf16x8 b0  = *(const bf16x8*)(xb + XOFF(lm,      c*4 + q));
                bf16x8 b1v = *(const bf16x8*)(xb + XOFF(16 + lm, c*4 + q));
                #pragma unroll
                for (int mt = 0; mt < 2; ++mt) {
                    acc[mt][0] = __builtin_amdgcn_mfma_f32_16x16x32_bf16(wA[mt][c], b0,  acc[mt][0], 0,0,0);
                    acc[mt][1] = __builtin_amdgcn_mfma_f32_16x16x32_bf16(wA[mt][c], b1v, acc[mt][1], 0,0,0);
                }
            }
        }
        float pv[2] = {0.f, 0.f};                  // epilogue: relu(h1+b1).u, fp32
        #pragma unroll
        for (int mt = 0; mt < 2; ++mt) {
            const int f0 = wave*32 + mt*16 + q*4;
            float4 bb = *(const float4*)&b1S[f0];
            float4 uu = *(const float4*)&uS[f0];
            #pragma unroll
            for (int nt = 0; nt < 2; ++nt) {
                float hx = fmaxf(acc[mt][nt][0] + bb.x, 0.f);
                float hy = fmaxf(acc[mt][nt][1] + bb.y, 0.f);
                float hz = fmaxf(acc[mt][nt][2] + bb.z, 0.f);
                float hw = fmaxf(acc[mt][nt][3] + bb.w, 0.f);
                pv[nt] += hx*uu.x + hy*uu.y + hz*uu.z + hw*uu.w;
            }
        }
        #pragma unroll
        for (int nt = 0; nt < 2; ++nt) {
            float v = pv[nt];
            v += __shfl_xor(v, 16);
            v += __shfl_xor(v, 32);
            if (lane < 16) red[wave][nt*16 + lane] = v;
        }
        if (tid < 32) {                            // meta writes for i+2 (slot p)
            colsS[p][tid] = m_ci;
            *(float4*)&posrel[p][tid][0] = m_pr;
        }
    }
    __syncthreads();
    if (tid < 32) {                                // final tile's out-store
        long e = ((long)bid + (long)(niter-1)*512)*32 + tid;
        if (e < E) {
            float s = Sv;
            #pragma unroll
            for (int w = 0; w < 8; ++w) s += red[w][tid];
            out[e] = s;
        }
    }
}

extern "C" void kernel_launch(void* const* d_in, const int* in_sizes, int n_in,
                              void* d_out, int out_size, void* d_ws, size_t ws_size,
                              hipStream_t stream)
{
    const float* pos_src = (const float*)d_in[0];
    const float* pos_tgt = (const float*)d_in[1];
    const float* latents = (const float*)d_in[2];
    const int*   rowi    = (const int*)d_in[3];
    const int*   coli    = (const int*)d_in[4];
    const float* Win     = (const float*)d_in[5];
    const float* b_in    = (const float*)d_in[6];
    const float* W1      = (const float*)d_in[7];
    const float* b1      = (const float*)d_in[8];
    const float* W2      = (const float*)d_in[9];
    const float* b2      = (const float*)d_in[10];
    const float* Wout    = (const float*)d_in[11];
    const float* b_out   = (const float*)d_in[12];
    float* out = (float*)d_out;
    const int E = in_sizes[3];
    const int ntiles = (E + 31) / 32;

    char* wp = (char*)d_ws;                  // packs ~264 KB + Y 51.2 MB
    char* Yc = wp + Y_OFF;

    pack_kernel<<<25, 256, 0, stream>>>(Win, W1, W2, Wout, b1, b2, b_out, wp);
    precompute_y<<<512, 512, 0, stream>>>(latents, b_in, wp, Yc);
    interp_main<<<512, 512, 0, stream>>>(pos_src, pos_tgt, rowi, coli,
                                         Win, wp, Yc, out, E, ntiles);
}